// Round 8
// baseline (380.091 us; speedup 1.0000x reference)
//
#include <hip/hip_runtime.h>
#include <math.h>

#define NH 12
#define DM 768
#define DH 64
#define SS 1024

typedef __attribute__((ext_vector_type(8))) short short8;
typedef __attribute__((ext_vector_type(4))) float floatx4;
typedef __attribute__((ext_vector_type(4))) unsigned short usv4;

__device__ __forceinline__ ushort f2bf(float f) {
    union { float f; unsigned u; } v; v.f = f;
    unsigned r = v.u + 0x7fffu + ((v.u >> 16) & 1u);
    return (ushort)(r >> 16);
}
__device__ __forceinline__ float bf2f(ushort u) {
    union { unsigned u; float f; } v; v.u = ((unsigned)u) << 16;
    return v.f;
}

__device__ __forceinline__ void gld_lds16(const ushort* g, ushort* l) {
    __builtin_amdgcn_global_load_lds(
        (const __attribute__((address_space(1))) unsigned int*)g,
        (__attribute__((address_space(3))) unsigned int*)l, 16, 0, 0);
}

// ws layout (ushort units):
//   Qb   : bf16 [8][12][1024][64] (x0.125)   @ 0          (6291456)
//   Kb   : bf16 [8][12][1024][64]            @ 6291456
//   Vtb  : bf16 [8][12][64][1024]            @ 12582912
//   xb   : bf16 [8192][768]                  @ 18874368
//   WbT  : bf16 [3][12 n][64 h][768 d]       @ 25165824   (1769472)
//   Zb   : bf16 [8 bp][12 n][1024 s][64 h]   @ 26935296   (6291456)
//   WObT : bf16 [768 d][768 k=(n,h)]         @ 33226752   (589824)
//   Zd   : bf16 [4 b][12 n][1024 s][64 h]    @ 33816576   (3145728)

// ---------------- prep: all input casts in one kernel ----------------
__global__ __launch_bounds__(256) void prep_k(
    const float* __restrict__ x0, const float* __restrict__ x1,
    const float* __restrict__ WQ, const float* __restrict__ WK, const float* __restrict__ WV,
    const float* __restrict__ WO,
    ushort* __restrict__ xb, ushort* __restrict__ WbT, ushort* __restrict__ WObT)
{
    __shared__ float T[64][68];
    const int bid = blockIdx.x;
    const int tid = threadIdx.x;
    if (bid < 3072) {
        const size_t e = ((size_t)bid * 256 + tid) * 8;
        const int m = (int)(e / DM), col = (int)(e % DM);
        const int p = (m >> 10) & 1, b = m >> 11, s = m & 1023;
        const float* src = ((p == 0) ? x0 : x1) + (size_t)b * (SS * DM) + (size_t)s * DM + col;
        float4 v0 = *(const float4*)(src);
        float4 v1 = *(const float4*)(src + 4);
        short8 o;
        o[0] = (short)f2bf(v0.x); o[1] = (short)f2bf(v0.y); o[2] = (short)f2bf(v0.z); o[3] = (short)f2bf(v0.w);
        o[4] = (short)f2bf(v1.x); o[5] = (short)f2bf(v1.y); o[6] = (short)f2bf(v1.z); o[7] = (short)f2bf(v1.w);
        *(short8*)(xb + e) = o;
        return;
    }
    const int di = tid >> 2, cg = tid & 3;
    if (bid < 3072 + 432) {
        const int idx = bid - 3072;
        const int tn = idx % 36, dt = idx / 36;
        const int t = tn / NH, n = tn % NH;
        const float* W = ((t == 0) ? WQ : (t == 1) ? WK : WV) + (size_t)n * (DM * DH);
        const int d0 = dt * 64;
#pragma unroll
        for (int j = 0; j < 4; j++) {
            const int c = cg * 16 + j * 4;
            float4 v = *(const float4*)(W + (size_t)(d0 + di) * DH + c);
            *(float4*)&T[di][c] = v;
        }
        __syncthreads();
        ushort* dst = WbT + (size_t)t * (NH * DH * DM) + (size_t)n * (DH * DM) + (size_t)di * DM + d0;
#pragma unroll
        for (int j = 0; j < 4; j++) {
            const int dc = cg * 16 + j * 4;
            usv4 o;
            o[0] = f2bf(T[dc + 0][di]); o[1] = f2bf(T[dc + 1][di]);
            o[2] = f2bf(T[dc + 2][di]); o[3] = f2bf(T[dc + 3][di]);
            *(usv4*)(dst + dc) = o;
        }
        return;
    }
    {
        const int idx = bid - 3072 - 432;
        const int kt = idx % 12, dt = idx / 12;
#pragma unroll
        for (int j = 0; j < 4; j++) {
            const int c = cg * 16 + j * 4;
            float4 v = *(const float4*)(WO + (size_t)(kt * 64 + di) * DM + dt * 64 + c);
            *(float4*)&T[di][c] = v;
        }
        __syncthreads();
        ushort* dst = WObT + (size_t)(dt * 64 + di) * DM + kt * 64;
#pragma unroll
        for (int j = 0; j < 4; j++) {
            const int dc = cg * 16 + j * 4;
            usv4 o;
            o[0] = f2bf(T[dc + 0][di]); o[1] = f2bf(T[dc + 1][di]);
            o[2] = f2bf(T[dc + 2][di]); o[3] = f2bf(T[dc + 3][di]);
            *(usv4*)(dst + dc) = o;
        }
    }
}

// ---------------- Kernel A: QKV MFMA GEMM (v3: BK=64, single-buffer) ----------------
// 12 K-steps instead of 24 -> barrier count halved (48 -> 24); LDS 32KB single-buf.
__global__ __launch_bounds__(256) void qkv_mfma_k(
    const ushort* __restrict__ xb, const ushort* __restrict__ WbT,
    const float* __restrict__ bQ, const float* __restrict__ bK, const float* __restrict__ bV,
    ushort* __restrict__ Qb, ushort* __restrict__ Kb, ushort* __restrict__ Vtb)
{
    __shared__ ushort As[128 * 64];
    __shared__ ushort Bs[128 * 64];
    const int tid = threadIdx.x;
    const int w = tid >> 6, lane = tid & 63;
    const int l16 = lane & 15, quad = lane >> 4;
    const int jt = blockIdx.x;          // 0..17
    const int mt = blockIdx.y;          // 0..63
    const int t = jt / 6;
    const int jb = (jt % 6) * 128;
    const int mbase = mt * 128;

    const ushort* Bt = WbT + (size_t)t * (DM * DM) + (size_t)jb * DM;

    const int sr8 = lane >> 3;      // 0..7  (row within 8-row chunk)
    const int su8 = lane & 7;       // 0..7  (16B unit within 128B row)

    floatx4 acc[2][8];
#pragma unroll
    for (int m = 0; m < 2; m++)
#pragma unroll
        for (int n = 0; n < 8; n++) acc[m][n] = (floatx4){0.f, 0.f, 0.f, 0.f};

    for (int kt = 0; kt < 12; kt++) {
        const int k0 = kt * 64;
        __syncthreads();
#pragma unroll
        for (int j = 0; j < 4; j++) {
            const int row = w * 32 + j * 8 + sr8;
            gld_lds16(xb + (size_t)(mbase + row) * DM + k0 + su8 * 8, As + (w * 32 + j * 8) * 64);
            gld_lds16(Bt + (size_t)row * DM + k0 + su8 * 8,           Bs + (w * 32 + j * 8) * 64);
        }
        asm volatile("s_waitcnt vmcnt(0)" ::: "memory");
        __syncthreads();

#pragma unroll
        for (int kk = 0; kk < 2; kk++) {
            const ushort* Ab = As + (w * 32 + l16) * 64 + kk * 32 + quad * 8;
            short8 a0 = *(const short8*)(Ab);
            short8 a1 = *(const short8*)(Ab + 16 * 64);
#pragma unroll
            for (int n = 0; n < 8; n++) {
                short8 b = *(const short8*)(Bs + (n * 16 + l16) * 64 + kk * 32 + quad * 8);
                acc[0][n] = __builtin_amdgcn_mfma_f32_16x16x32_bf16(a0, b, acc[0][n], 0, 0, 0);
                acc[1][n] = __builtin_amdgcn_mfma_f32_16x16x32_bf16(a1, b, acc[1][n], 0, 0, 0);
            }
        }
    }

    const float* bias = (t == 0) ? bQ : (t == 1) ? bK : bV;
#pragma unroll
    for (int m = 0; m < 2; m++) {
        const int mrow0 = mbase + w * 32 + m * 16 + quad * 4;
        const int bp = mrow0 >> 10;
        const int s0 = mrow0 & 1023;
#pragma unroll
        for (int n = 0; n < 8; n++) {
            const int col = jb + n * 16 + l16;
            const int head = col >> 6, h = col & 63;
            const size_t hb = ((size_t)bp * NH + head) * (SS * DH);
            const float bv = bias[head * DH + h];
            if (t == 0) {
#pragma unroll
                for (int r = 0; r < 4; r++)
                    Qb[hb + (size_t)(s0 + r) * DH + h] = f2bf((acc[m][n][r] + bv) * 0.125f);
            } else if (t == 1) {
#pragma unroll
                for (int r = 0; r < 4; r++)
                    Kb[hb + (size_t)(s0 + r) * DH + h] = f2bf(acc[m][n][r] + bv);
            } else {
                usv4 o;
#pragma unroll
                for (int r = 0; r < 4; r++) o[r] = f2bf(acc[m][n][r] + bv);
                *(usv4*)(Vtb + hb + (size_t)h * SS + s0) = o;
            }
        }
    }
}

// ---------------- Kernel B: MFMA flash attention (unchanged v4) ----------------
__global__ __launch_bounds__(256) void attn_mfma_k(
    const ushort* __restrict__ Qb, const ushort* __restrict__ Kb,
    const ushort* __restrict__ Vtb, ushort* __restrict__ Zb)
{
    __shared__ __align__(16) ushort Ks[64 * 64];
    __shared__ __align__(16) ushort Vs[64 * 64];
    __shared__ __align__(16) ushort P_lds[4][16][72];

    const int bid  = blockIdx.x;                     // 0..767
    const int head = (bid & 7) + ((bid >> 6) << 3);  // bid%8 == head%8 -> XCD affinity
    const int qpair = (bid >> 3) & 7;                // 0..7
    const int wave = threadIdx.x >> 6;
    const int lane = threadIdx.x & 63;
    const int quad = lane >> 4;
    const int l16  = lane & 15;

    const size_t hb = (size_t)head * (SS * DH);
    const ushort* Qh = Qb + hb;
    const ushort* Kh = Kb + hb;
    const ushort* Vh = Vtb + hb;

    const int srl = lane >> 3;      // 0..7
    const int su  = lane & 7;       // 16B unit within a 128B row

#pragma unroll 1
    for (int half = 0; half < 2; half++) {
        const int qtile = (half == 0) ? (15 - qpair) : qpair;   // 64-row tile
        const int qbase = qtile * 64 + wave * 16;
        const int q_lane = qbase + l16;

        short8 b_q0 = *(const short8*)(Qh + (size_t)(qbase + l16) * DH + quad * 8);
        short8 b_q1 = *(const short8*)(Qh + (size_t)(qbase + l16) * DH + 32 + quad * 8);

        floatx4 o[4];
        float m_run = -1e30f, l_run = 0.f;
#pragma unroll
        for (int hg = 0; hg < 4; hg++) o[hg] = (floatx4){0.f, 0.f, 0.f, 0.f};

        const int kb_last = qtile;
        for (int kb = 0; kb <= kb_last; kb++) {
            __syncthreads();
#pragma unroll
            for (int j = 0; j < 2; j++) {
                const int rl  = j * 8 + srl;
                const int row = wave * 16 + rl;
                const int uu  = su ^ (rl & 7);
                gld_lds16(Kh + (size_t)(kb * 64 + row) * DH + uu * 8,
                          Ks + wave * 1024 + j * 512);
                gld_lds16(Vh + (size_t)row * SS + kb * 64 + uu * 8,
                          Vs + wave * 1024 + j * 512);
            }
            asm volatile("s_waitcnt vmcnt(0)" ::: "memory");
            __syncthreads();

            floatx4 c[4];
#pragma unroll
            for (int kg = 0; kg < 4; kg++) {
                const int r = kg * 16 + l16;
                short8 k0 = *(const short8*)(Ks + r * 64 + ((quad ^ (r & 7)) * 8));
                short8 k1 = *(const short8*)(Ks + r * 64 + (((quad + 4) ^ (r & 7)) * 8));
                floatx4 cc = (floatx4){0.f, 0.f, 0.f, 0.f};
                cc = __builtin_amdgcn_mfma_f32_16x16x32_bf16(k0, b_q0, cc, 0, 0, 0);
                cc = __builtin_amdgcn_mfma_f32_16x16x32_bf16(k1, b_q1, cc, 0, 0, 0);
                c[kg] = cc;
            }
            if (kb == kb_last) {
#pragma unroll
                for (int kg = 0; kg < 4; kg++)
#pragma unroll
                    for (int r = 0; r < 4; r++) {
                        const int key = kb * 64 + kg * 16 + quad * 4 + r;
                        if (key > q_lane) c[kg][r] = -1e30f;
                    }
            }

            float mk0 = fmaxf(fmaxf(c[0][0], c[0][1]), fmaxf(c[0][2], c[0][3]));
            float mk1 = fmaxf(fmaxf(c[1][0], c[1][1]), fmaxf(c[1][2], c[1][3]));
            float mk2 = fmaxf(fmaxf(c[2][0], c[2][1]), fmaxf(c[2][2], c[2][3]));
            float mk3 = fmaxf(fmaxf(c[3][0], c[3][1]), fmaxf(c[3][2], c[3][3]));
            float mt = fmaxf(fmaxf(mk0, mk1), fmaxf(mk2, mk3));
            mt = fmaxf(mt, __shfl_xor(mt, 16, 64));
            mt = fmaxf(mt, __shfl_xor(mt, 32, 64));
            const float m_new = fmaxf(m_run, mt);
            const float alpha = __expf(m_run - m_new);
            m_run = m_new;

            float rs = 0.f;
#pragma unroll
            for (int kg = 0; kg < 4; kg++) {
                const float p0 = __expf(c[kg][0] - m_new);
                const float p1 = __expf(c[kg][1] - m_new);
                const float p2 = __expf(c[kg][2] - m_new);
                const float p3 = __expf(c[kg][3] - m_new);
                rs += (p0 + p1) + (p2 + p3);
                const unsigned w0 = ((unsigned)f2bf(p1) << 16) | (unsigned)f2bf(p0);
                const unsigned w1 = ((unsigned)f2bf(p3) << 16) | (unsigned)f2bf(p2);
                *(unsigned*)&P_lds[wave][l16][kg * 16 + quad * 4]     = w0;
                *(unsigned*)&P_lds[wave][l16][kg * 16 + quad * 4 + 2] = w1;
            }
            rs += __shfl_xor(rs, 16, 64);
            rs += __shfl_xor(rs, 32, 64);
            l_run = l_run * alpha + rs;

            float a_o[4];
#pragma unroll
            for (int r = 0; r < 4; r++) a_o[r] = __shfl(alpha, quad * 4 + r, 64);
#pragma unroll
            for (int hg = 0; hg < 4; hg++)
#pragma unroll
                for (int r = 0; r < 4; r++) o[hg][r] *= a_o[r];

            asm volatile("s_waitcnt lgkmcnt(0)" ::: "memory");
            short8 ap0 = *(const short8*)&P_lds[wave][l16][quad * 8];
            short8 ap1 = *(const short8*)&P_lds[wave][l16][32 + quad * 8];
#pragma unroll
            for (int hg = 0; hg < 4; hg++) {
                const int h = hg * 16 + l16;
                short8 bv0 = *(const short8*)(Vs + h * 64 + ((quad ^ (h & 7)) * 8));
                short8 bv1 = *(const short8*)(Vs + h * 64 + (((quad + 4) ^ (h & 7)) * 8));
                o[hg] = __builtin_amdgcn_mfma_f32_16x16x32_bf16(ap0, bv0, o[hg], 0, 0, 0);
                o[hg] = __builtin_amdgcn_mfma_f32_16x16x32_bf16(ap1, bv1, o[hg], 0, 0, 0);
            }
            asm volatile("s_waitcnt lgkmcnt(0)" ::: "memory");
        }

        const float inv = 1.f / l_run;
        float inv_o[4];
#pragma unroll
        for (int r = 0; r < 4; r++) inv_o[r] = __shfl(inv, quad * 4 + r, 64);
#pragma unroll
        for (int hg = 0; hg < 4; hg++)
#pragma unroll
            for (int r = 0; r < 4; r++)
                Zb[hb + (size_t)(qbase + quad * 4 + r) * DH + hg * 16 + l16] = f2bf(o[hg][r] * inv_o[r]);
    }
}

// ---------------- Zd = Z(p=0) - Z(p=1) per head ----------------
__global__ __launch_bounds__(256) void zdiff_k(
    const ushort* __restrict__ Zb, ushort* __restrict__ Zd)
{
    const size_t e = ((size_t)blockIdx.x * 256 + threadIdx.x) * 8;
    const int bk = (int)(e >> 16);           // b*12+k
    const int off = (int)(e & 65535);
    const int b_ = bk / NH, k = bk % NH;
    const ushort* z0 = Zb + ((size_t)(b_ * 2) * NH + k) * (SS * DH) + off;
    const ushort* z1 = Zb + ((size_t)(b_ * 2 + 1) * NH + k) * (SS * DH) + off;
    short8 a = *(const short8*)z0;
    short8 c = *(const short8*)z1;
    short8 o;
#pragma unroll
    for (int i = 0; i < 8; i++)
        o[i] = (short)f2bf(bf2f((ushort)a[i]) - bf2f((ushort)c[i]));
    *(short8*)(Zd + e) = o;
}

// ---------------- O1: planes 0,1 (K=768 GEMM, BK=64) ----------------
// grid (6 jb, 16 q0, 8 z=b*2+pp) = 768 blocks (3/CU, was 1.5).
__global__ __launch_bounds__(256) void outproj1_k(
    const ushort* __restrict__ Zb, const ushort* __restrict__ WObT,
    const float* __restrict__ bO, float* __restrict__ out)
{
    __shared__ ushort As[64 * 64];
    __shared__ ushort Bs[128 * 64];
    const int tid = threadIdx.x;
    const int w = tid >> 6, lane = tid & 63;
    const int l16 = lane & 15, quad = lane >> 4;
    const int jb = blockIdx.x * 128;
    const int q0 = blockIdx.y * 64;
    const int b_ = blockIdx.z >> 1;
    const int pp = blockIdx.z & 1;

    const ushort* Zp = Zb + (size_t)(b_ * 2 + pp) * (NH * SS * DH);
    const int sr8 = lane >> 3;      // 0..7
    const int su8 = lane & 7;       // 0..7

    floatx4 acc[8];
#pragma unroll
    for (int n = 0; n < 8; n++) acc[n] = (floatx4){0.f, 0.f, 0.f, 0.f};

    for (int kt = 0; kt < 12; kt++) {
        const int k0 = kt * 64;
        __syncthreads();
#pragma unroll
        for (int j = 0; j < 2; j++) {       // A: 64 q-rows x 64 k
            const int row = w * 16 + j * 8 + sr8;
            gld_lds16(Zp + (size_t)kt * (SS * DH) + (size_t)(q0 + row) * DH + su8 * 8,
                      As + (w * 16 + j * 8) * 64);
        }
#pragma unroll
        for (int j = 0; j < 4; j++) {       // B: 128 d-rows x 64 k
            const int row = w * 32 + j * 8 + sr8;
            gld_lds16(WObT + (size_t)(jb + row) * DM + k0 + su8 * 8,
                      Bs + (w * 32 + j * 8) * 64);
        }
        asm volatile("s_waitcnt vmcnt(0)" ::: "memory");
        __syncthreads();

#pragma unroll
        for (int kk = 0; kk < 2; kk++) {
            short8 a = *(const short8*)(As + (w * 16 + l16) * 64 + kk * 32 + quad * 8);
#pragma unroll
            for (int n = 0; n < 8; n++) {
                short8 b = *(const short8*)(Bs + (n * 16 + l16) * 64 + kk * 32 + quad * 8);
                acc[n] = __builtin_amdgcn_mfma_f32_16x16x32_bf16(a, b, acc[n], 0, 0, 0);
            }
        }
    }

    float* obase = out + ((size_t)(b_ * 14 + pp) * SS) * DM;
    const int qr = q0 + w * 16 + quad * 4;
#pragma unroll
    for (int n = 0; n < 8; n++) {
        const int d = jb + n * 16 + l16;
        const float bv = bO[d];
#pragma unroll
        for (int r = 0; r < 4; r++)
            obase[(size_t)(qr + r) * DM + d] = acc[n][r] + bv;
    }
}

// ---------------- O2: planes 2..13 (per-head K=64 rank-update) ----------------
// grid (6 jb, 16 q0, 48 z=b*12+k) = 4608 blocks (18/CU). One staging phase,
// 16 MFMA/wave, s1 re-read from out plane b*14+1 (L3-resident, written by O1).
__global__ __launch_bounds__(256) void outproj2_k(
    const ushort* __restrict__ Zd, const ushort* __restrict__ WObT,
    const float* __restrict__ out_s1, float* __restrict__ out)
{
    __shared__ ushort As[64 * 64];
    __shared__ ushort Bs[128 * 64];
    const int tid = threadIdx.x;
    const int w = tid >> 6, lane = tid & 63;
    const int l16 = lane & 15, quad = lane >> 4;
    const int jb = blockIdx.x * 128;
    const int q0 = blockIdx.y * 64;
    const int b_ = blockIdx.z / NH;
    const int k  = blockIdx.z % NH;

    const ushort* Zdk = Zd + (size_t)(b_ * NH + k) * (SS * DH);
    const int sr8 = lane >> 3;
    const int su8 = lane & 7;

#pragma unroll
    for (int j = 0; j < 2; j++) {       // A: 64 q-rows x 64 h
        const int row = w * 16 + j * 8 + sr8;
        gld_lds16(Zdk + (size_t)(q0 + row) * DH + su8 * 8, As + (w * 16 + j * 8) * 64);
    }
#pragma unroll
    for (int j = 0; j < 4; j++) {       // B: 128 d-rows x 64 h (cols k*64..)
        const int row = w * 32 + j * 8 + sr8;
        gld_lds16(WObT + (size_t)(jb + row) * DM + k * DH + su8 * 8,
                  Bs + (w * 32 + j * 8) * 64);
    }
    asm volatile("s_waitcnt vmcnt(0)" ::: "memory");
    __syncthreads();

    floatx4 acc[8];
#pragma unroll
    for (int n = 0; n < 8; n++) acc[n] = (floatx4){0.f, 0.f, 0.f, 0.f};
#pragma unroll
    for (int kk = 0; kk < 2; kk++) {
        short8 a = *(const short8*)(As + (w * 16 + l16) * 64 + kk * 32 + quad * 8);
#pragma unroll
        for (int n = 0; n < 8; n++) {
            short8 b = *(const short8*)(Bs + (n * 16 + l16) * 64 + kk * 32 + quad * 8);
            acc[n] = __builtin_amdgcn_mfma_f32_16x16x32_bf16(a, b, acc[n], 0, 0, 0);
        }
    }

    const int qr = q0 + w * 16 + quad * 4;
    const float* s1base = out_s1 + ((size_t)(b_ * 14 + 1) * SS) * DM;
    float* obase = out + ((size_t)(b_ * 14 + 2 + k) * SS) * DM;
#pragma unroll
    for (int n = 0; n < 8; n++) {
        const int d = jb + n * 16 + l16;
#pragma unroll
        for (int r = 0; r < 4; r++) {
            const float s1 = s1base[(size_t)(qr + r) * DM + d];
            obase[(size_t)(qr + r) * DM + d] = acc[n][r] + s1;
        }
    }
}

extern "C" void kernel_launch(void* const* d_in, const int* in_sizes, int n_in,
                              void* d_out, int out_size, void* d_ws, size_t ws_size,
                              hipStream_t stream)
{
    const float* x0 = (const float*)d_in[0];
    const float* x1 = (const float*)d_in[1];
    const float* WQ = (const float*)d_in[2];
    const float* bQ = (const float*)d_in[3];
    const float* WK = (const float*)d_in[4];
    const float* bK = (const float*)d_in[5];
    const float* WV = (const float*)d_in[6];
    const float* bV = (const float*)d_in[7];
    const float* WO = (const float*)d_in[8];
    const float* bO = (const float*)d_in[9];
    float* out = (float*)d_out;

    ushort* ub   = (ushort*)d_ws;
    ushort* Qb   = ub;                        // 6291456
    ushort* Kb   = Qb + 6291456;
    ushort* Vtb  = Kb + 6291456;
    ushort* xb   = Vtb + 6291456;
    ushort* WbT  = xb + 6291456;              // 1769472
    ushort* Zb   = WbT + 1769472;             // 6291456
    ushort* WObT = Zb + 6291456;              // 589824
    ushort* Zd   = WObT + 589824;             // 3145728

    prep_k<<<dim3(3648), 256, 0, stream>>>(x0, x1, WQ, WK, WV, WO, xb, WbT, WObT);
    qkv_mfma_k<<<dim3(18, 64), 256, 0, stream>>>(xb, WbT, bQ, bK, bV, Qb, Kb, Vtb);
    attn_mfma_k<<<dim3(768), 256, 0, stream>>>(Qb, Kb, Vtb, Zb);
    zdiff_k<<<dim3(1536), 256, 0, stream>>>(Zb, Zd);
    outproj1_k<<<dim3(6, 16, 8), 256, 0, stream>>>(Zb, WObT, bO, out);
    outproj2_k<<<dim3(6, 16, 48), 256, 0, stream>>>(Zd, WObT, out, out);
}

// Round 9
// 352.454 us; speedup vs baseline: 1.0784x; 1.0784x over previous
//
#include <hip/hip_runtime.h>
#include <math.h>

#define NH 12
#define DM 768
#define DH 64
#define SS 1024

typedef __attribute__((ext_vector_type(8))) short short8;
typedef __attribute__((ext_vector_type(4))) float floatx4;
typedef __attribute__((ext_vector_type(4))) unsigned short usv4;

__device__ __forceinline__ ushort f2bf(float f) {
    union { float f; unsigned u; } v; v.f = f;
    unsigned r = v.u + 0x7fffu + ((v.u >> 16) & 1u);
    return (ushort)(r >> 16);
}
__device__ __forceinline__ float bf2f(ushort u) {
    union { unsigned u; float f; } v; v.u = ((unsigned)u) << 16;
    return v.f;
}

__device__ __forceinline__ void gld_lds16(const ushort* g, ushort* l) {
    __builtin_amdgcn_global_load_lds(
        (const __attribute__((address_space(1))) unsigned int*)g,
        (__attribute__((address_space(3))) unsigned int*)l, 16, 0, 0);
}

// ws layout (ushort units):
//   Qb   : bf16 [8][12][1024][64] (x0.125)   @ 0          (6291456)
//   Kb   : bf16 [8][12][1024][64]            @ 6291456
//   Vtb  : bf16 [8][12][64][1024]            @ 12582912
//   xb   : bf16 [8192][768]                  @ 18874368
//   WbT  : bf16 [3][12 n][64 h][768 d]       @ 25165824   (1769472)
//   Zb   : bf16 [8 bp][12 n][1024 s][64 h]   @ 26935296   (6291456)
//   WObT : bf16 [768 d][768 k=(n,h)]         @ 33226752   (589824)
//   Zd   : bf16 [4 b][12 n][1024 s][64 h]    @ 33816576   (3145728)

// ---------------- prep: all input casts in one kernel ----------------
__global__ __launch_bounds__(256) void prep_k(
    const float* __restrict__ x0, const float* __restrict__ x1,
    const float* __restrict__ WQ, const float* __restrict__ WK, const float* __restrict__ WV,
    const float* __restrict__ WO,
    ushort* __restrict__ xb, ushort* __restrict__ WbT, ushort* __restrict__ WObT)
{
    __shared__ float T[64][68];
    const int bid = blockIdx.x;
    const int tid = threadIdx.x;
    if (bid < 3072) {
        const size_t e = ((size_t)bid * 256 + tid) * 8;
        const int m = (int)(e / DM), col = (int)(e % DM);
        const int p = (m >> 10) & 1, b = m >> 11, s = m & 1023;
        const float* src = ((p == 0) ? x0 : x1) + (size_t)b * (SS * DM) + (size_t)s * DM + col;
        float4 v0 = *(const float4*)(src);
        float4 v1 = *(const float4*)(src + 4);
        short8 o;
        o[0] = (short)f2bf(v0.x); o[1] = (short)f2bf(v0.y); o[2] = (short)f2bf(v0.z); o[3] = (short)f2bf(v0.w);
        o[4] = (short)f2bf(v1.x); o[5] = (short)f2bf(v1.y); o[6] = (short)f2bf(v1.z); o[7] = (short)f2bf(v1.w);
        *(short8*)(xb + e) = o;
        return;
    }
    const int di = tid >> 2, cg = tid & 3;
    if (bid < 3072 + 432) {
        const int idx = bid - 3072;
        const int tn = idx % 36, dt = idx / 36;
        const int t = tn / NH, n = tn % NH;
        const float* W = ((t == 0) ? WQ : (t == 1) ? WK : WV) + (size_t)n * (DM * DH);
        const int d0 = dt * 64;
#pragma unroll
        for (int j = 0; j < 4; j++) {
            const int c = cg * 16 + j * 4;
            float4 v = *(const float4*)(W + (size_t)(d0 + di) * DH + c);
            *(float4*)&T[di][c] = v;
        }
        __syncthreads();
        ushort* dst = WbT + (size_t)t * (NH * DH * DM) + (size_t)n * (DH * DM) + (size_t)di * DM + d0;
#pragma unroll
        for (int j = 0; j < 4; j++) {
            const int dc = cg * 16 + j * 4;
            usv4 o;
            o[0] = f2bf(T[dc + 0][di]); o[1] = f2bf(T[dc + 1][di]);
            o[2] = f2bf(T[dc + 2][di]); o[3] = f2bf(T[dc + 3][di]);
            *(usv4*)(dst + dc) = o;
        }
        return;
    }
    {
        const int idx = bid - 3072 - 432;
        const int kt = idx % 12, dt = idx / 12;
#pragma unroll
        for (int j = 0; j < 4; j++) {
            const int c = cg * 16 + j * 4;
            float4 v = *(const float4*)(WO + (size_t)(kt * 64 + di) * DM + dt * 64 + c);
            *(float4*)&T[di][c] = v;
        }
        __syncthreads();
        ushort* dst = WObT + (size_t)(dt * 64 + di) * DM + kt * 64;
#pragma unroll
        for (int j = 0; j < 4; j++) {
            const int dc = cg * 16 + j * 4;
            usv4 o;
            o[0] = f2bf(T[dc + 0][di]); o[1] = f2bf(T[dc + 1][di]);
            o[2] = f2bf(T[dc + 2][di]); o[3] = f2bf(T[dc + 3][di]);
            *(usv4*)(dst + dc) = o;
        }
    }
}

// ---------------- Kernel A: QKV MFMA GEMM (R5 form: BK=32, 16KB LDS) ----------------
__global__ __launch_bounds__(256) void qkv_mfma_k(
    const ushort* __restrict__ xb, const ushort* __restrict__ WbT,
    const float* __restrict__ bQ, const float* __restrict__ bK, const float* __restrict__ bV,
    ushort* __restrict__ Qb, ushort* __restrict__ Kb, ushort* __restrict__ Vtb)
{
    __shared__ ushort As[128 * 32];
    __shared__ ushort Bs[128 * 32];
    const int tid = threadIdx.x;
    const int w = tid >> 6, lane = tid & 63;
    const int l16 = lane & 15, quad = lane >> 4;
    const int jt = blockIdx.x;          // 0..17
    const int mt = blockIdx.y;          // 0..63
    const int t = jt / 6;
    const int jb = (jt % 6) * 128;
    const int mbase = mt * 128;

    const ushort* Bt = WbT + (size_t)t * (DM * DM) + (size_t)jb * DM;

    const int srow = (lane >> 2);
    const int scol = (lane & 3) * 8;
    const ushort* gA0 = xb + (size_t)(mbase + w * 32 + srow) * DM + scol;
    const ushort* gB0 = Bt + (size_t)(w * 32 + srow) * DM + scol;
    ushort* lA0 = As + (w * 32) * 32;
    ushort* lB0 = Bs + (w * 32) * 32;

    floatx4 acc[2][8];
#pragma unroll
    for (int m = 0; m < 2; m++)
#pragma unroll
        for (int n = 0; n < 8; n++) acc[m][n] = (floatx4){0.f, 0.f, 0.f, 0.f};

    for (int kt = 0; kt < 24; kt++) {
        const int k0 = kt * 32;
        __syncthreads();
        gld_lds16(gA0 + k0, lA0);
        gld_lds16(gA0 + (size_t)16 * DM + k0, lA0 + 16 * 32);
        gld_lds16(gB0 + k0, lB0);
        gld_lds16(gB0 + (size_t)16 * DM + k0, lB0 + 16 * 32);
        asm volatile("s_waitcnt vmcnt(0)" ::: "memory");
        __syncthreads();

        const ushort* Ab = As + (w * 32 + l16) * 32 + quad * 8;
        short8 a0 = *(const short8*)(Ab);
        short8 a1 = *(const short8*)(Ab + 16 * 32);
#pragma unroll
        for (int n = 0; n < 8; n++) {
            short8 b = *(const short8*)(Bs + (n * 16 + l16) * 32 + quad * 8);
            acc[0][n] = __builtin_amdgcn_mfma_f32_16x16x32_bf16(a0, b, acc[0][n], 0, 0, 0);
            acc[1][n] = __builtin_amdgcn_mfma_f32_16x16x32_bf16(a1, b, acc[1][n], 0, 0, 0);
        }
    }

    const float* bias = (t == 0) ? bQ : (t == 1) ? bK : bV;
#pragma unroll
    for (int m = 0; m < 2; m++) {
        const int mrow0 = mbase + w * 32 + m * 16 + quad * 4;
        const int bp = mrow0 >> 10;
        const int s0 = mrow0 & 1023;
#pragma unroll
        for (int n = 0; n < 8; n++) {
            const int col = jb + n * 16 + l16;
            const int head = col >> 6, h = col & 63;
            const size_t hb = ((size_t)bp * NH + head) * (SS * DH);
            const float bv = bias[head * DH + h];
            if (t == 0) {
#pragma unroll
                for (int r = 0; r < 4; r++)
                    Qb[hb + (size_t)(s0 + r) * DH + h] = f2bf((acc[m][n][r] + bv) * 0.125f);
            } else if (t == 1) {
#pragma unroll
                for (int r = 0; r < 4; r++)
                    Kb[hb + (size_t)(s0 + r) * DH + h] = f2bf(acc[m][n][r] + bv);
            } else {
                usv4 o;
#pragma unroll
                for (int r = 0; r < 4; r++) o[r] = f2bf(acc[m][n][r] + bv);
                *(usv4*)(Vtb + hb + (size_t)h * SS + s0) = o;
            }
        }
    }
}

// ---------------- Kernel B: MFMA flash attention (unchanged v4) ----------------
__global__ __launch_bounds__(256) void attn_mfma_k(
    const ushort* __restrict__ Qb, const ushort* __restrict__ Kb,
    const ushort* __restrict__ Vtb, ushort* __restrict__ Zb)
{
    __shared__ __align__(16) ushort Ks[64 * 64];
    __shared__ __align__(16) ushort Vs[64 * 64];
    __shared__ __align__(16) ushort P_lds[4][16][72];

    const int bid  = blockIdx.x;                     // 0..767
    const int head = (bid & 7) + ((bid >> 6) << 3);  // bid%8 == head%8 -> XCD affinity
    const int qpair = (bid >> 3) & 7;                // 0..7
    const int wave = threadIdx.x >> 6;
    const int lane = threadIdx.x & 63;
    const int quad = lane >> 4;
    const int l16  = lane & 15;

    const size_t hb = (size_t)head * (SS * DH);
    const ushort* Qh = Qb + hb;
    const ushort* Kh = Kb + hb;
    const ushort* Vh = Vtb + hb;

    const int srl = lane >> 3;      // 0..7
    const int su  = lane & 7;       // 16B unit within a 128B row

#pragma unroll 1
    for (int half = 0; half < 2; half++) {
        const int qtile = (half == 0) ? (15 - qpair) : qpair;   // 64-row tile
        const int qbase = qtile * 64 + wave * 16;
        const int q_lane = qbase + l16;

        short8 b_q0 = *(const short8*)(Qh + (size_t)(qbase + l16) * DH + quad * 8);
        short8 b_q1 = *(const short8*)(Qh + (size_t)(qbase + l16) * DH + 32 + quad * 8);

        floatx4 o[4];
        float m_run = -1e30f, l_run = 0.f;
#pragma unroll
        for (int hg = 0; hg < 4; hg++) o[hg] = (floatx4){0.f, 0.f, 0.f, 0.f};

        const int kb_last = qtile;
        for (int kb = 0; kb <= kb_last; kb++) {
            __syncthreads();
#pragma unroll
            for (int j = 0; j < 2; j++) {
                const int rl  = j * 8 + srl;
                const int row = wave * 16 + rl;
                const int uu  = su ^ (rl & 7);
                gld_lds16(Kh + (size_t)(kb * 64 + row) * DH + uu * 8,
                          Ks + wave * 1024 + j * 512);
                gld_lds16(Vh + (size_t)row * SS + kb * 64 + uu * 8,
                          Vs + wave * 1024 + j * 512);
            }
            asm volatile("s_waitcnt vmcnt(0)" ::: "memory");
            __syncthreads();

            floatx4 c[4];
#pragma unroll
            for (int kg = 0; kg < 4; kg++) {
                const int r = kg * 16 + l16;
                short8 k0 = *(const short8*)(Ks + r * 64 + ((quad ^ (r & 7)) * 8));
                short8 k1 = *(const short8*)(Ks + r * 64 + (((quad + 4) ^ (r & 7)) * 8));
                floatx4 cc = (floatx4){0.f, 0.f, 0.f, 0.f};
                cc = __builtin_amdgcn_mfma_f32_16x16x32_bf16(k0, b_q0, cc, 0, 0, 0);
                cc = __builtin_amdgcn_mfma_f32_16x16x32_bf16(k1, b_q1, cc, 0, 0, 0);
                c[kg] = cc;
            }
            if (kb == kb_last) {
#pragma unroll
                for (int kg = 0; kg < 4; kg++)
#pragma unroll
                    for (int r = 0; r < 4; r++) {
                        const int key = kb * 64 + kg * 16 + quad * 4 + r;
                        if (key > q_lane) c[kg][r] = -1e30f;
                    }
            }

            float mk0 = fmaxf(fmaxf(c[0][0], c[0][1]), fmaxf(c[0][2], c[0][3]));
            float mk1 = fmaxf(fmaxf(c[1][0], c[1][1]), fmaxf(c[1][2], c[1][3]));
            float mk2 = fmaxf(fmaxf(c[2][0], c[2][1]), fmaxf(c[2][2], c[2][3]));
            float mk3 = fmaxf(fmaxf(c[3][0], c[3][1]), fmaxf(c[3][2], c[3][3]));
            float mt = fmaxf(fmaxf(mk0, mk1), fmaxf(mk2, mk3));
            mt = fmaxf(mt, __shfl_xor(mt, 16, 64));
            mt = fmaxf(mt, __shfl_xor(mt, 32, 64));
            const float m_new = fmaxf(m_run, mt);
            const float alpha = __expf(m_run - m_new);
            m_run = m_new;

            float rs = 0.f;
#pragma unroll
            for (int kg = 0; kg < 4; kg++) {
                const float p0 = __expf(c[kg][0] - m_new);
                const float p1 = __expf(c[kg][1] - m_new);
                const float p2 = __expf(c[kg][2] - m_new);
                const float p3 = __expf(c[kg][3] - m_new);
                rs += (p0 + p1) + (p2 + p3);
                const unsigned w0 = ((unsigned)f2bf(p1) << 16) | (unsigned)f2bf(p0);
                const unsigned w1 = ((unsigned)f2bf(p3) << 16) | (unsigned)f2bf(p2);
                *(unsigned*)&P_lds[wave][l16][kg * 16 + quad * 4]     = w0;
                *(unsigned*)&P_lds[wave][l16][kg * 16 + quad * 4 + 2] = w1;
            }
            rs += __shfl_xor(rs, 16, 64);
            rs += __shfl_xor(rs, 32, 64);
            l_run = l_run * alpha + rs;

            float a_o[4];
#pragma unroll
            for (int r = 0; r < 4; r++) a_o[r] = __shfl(alpha, quad * 4 + r, 64);
#pragma unroll
            for (int hg = 0; hg < 4; hg++)
#pragma unroll
                for (int r = 0; r < 4; r++) o[hg][r] *= a_o[r];

            asm volatile("s_waitcnt lgkmcnt(0)" ::: "memory");
            short8 ap0 = *(const short8*)&P_lds[wave][l16][quad * 8];
            short8 ap1 = *(const short8*)&P_lds[wave][l16][32 + quad * 8];
#pragma unroll
            for (int hg = 0; hg < 4; hg++) {
                const int h = hg * 16 + l16;
                short8 bv0 = *(const short8*)(Vs + h * 64 + ((quad ^ (h & 7)) * 8));
                short8 bv1 = *(const short8*)(Vs + h * 64 + (((quad + 4) ^ (h & 7)) * 8));
                o[hg] = __builtin_amdgcn_mfma_f32_16x16x32_bf16(ap0, bv0, o[hg], 0, 0, 0);
                o[hg] = __builtin_amdgcn_mfma_f32_16x16x32_bf16(ap1, bv1, o[hg], 0, 0, 0);
            }
            asm volatile("s_waitcnt lgkmcnt(0)" ::: "memory");
        }

        const float inv = 1.f / l_run;
        float inv_o[4];
#pragma unroll
        for (int r = 0; r < 4; r++) inv_o[r] = __shfl(inv, quad * 4 + r, 64);
#pragma unroll
        for (int hg = 0; hg < 4; hg++)
#pragma unroll
            for (int r = 0; r < 4; r++)
                Zb[hb + (size_t)(qbase + quad * 4 + r) * DH + hg * 16 + l16] = f2bf(o[hg][r] * inv_o[r]);
    }
}

// ---------------- Zd = Z(p=0) - Z(p=1) per head ----------------
__global__ __launch_bounds__(256) void zdiff_k(
    const ushort* __restrict__ Zb, ushort* __restrict__ Zd)
{
    const size_t e = ((size_t)blockIdx.x * 256 + threadIdx.x) * 8;
    const int bk = (int)(e >> 16);           // b*12+k
    const int off = (int)(e & 65535);
    const int b_ = bk / NH, k = bk % NH;
    const ushort* z0 = Zb + ((size_t)(b_ * 2) * NH + k) * (SS * DH) + off;
    const ushort* z1 = Zb + ((size_t)(b_ * 2 + 1) * NH + k) * (SS * DH) + off;
    short8 a = *(const short8*)z0;
    short8 c = *(const short8*)z1;
    short8 o;
#pragma unroll
    for (int i = 0; i < 8; i++)
        o[i] = (short)f2bf(bf2f((ushort)a[i]) - bf2f((ushort)c[i]));
    *(short8*)(Zd + e) = o;
}

// ---------------- Fused output projection: all 14 planes ----------------
// v3: N-tile 128 -> 64 (grid (12,16,4) = 768 blocks = 3/CU, was 1.5/CU).
// Same R5 phase structure; s1 held in registers (no extra traffic).
__global__ __launch_bounds__(256) void outproj_k(
    const ushort* __restrict__ Zb, const ushort* __restrict__ Zd,
    const ushort* __restrict__ WObT, const float* __restrict__ bO,
    float* __restrict__ out)
{
    __shared__ ushort As[64 * 32];
    __shared__ ushort Bs[64 * 32];
    const int tid = threadIdx.x;
    const int w = tid >> 6, lane = tid & 63;
    const int l16 = lane & 15, quad = lane >> 4;
    const int jb = blockIdx.x * 64;
    const int q0 = blockIdx.y * 64;
    const int b_ = blockIdx.z;

    const int srow = lane >> 2;             // 0..15
    const int scol = (lane & 3) * 8;        // ushort offset within 32-k chunk
    const int arow = q0 + w * 16 + srow;    // global q row this lane stages
    const ushort* gB = WObT + (size_t)(jb + w * 16 + srow) * DM + scol;
    ushort* lA = As + (w * 16) * 32;
    ushort* lB = Bs + (w * 16) * 32;

    const ushort* Afrag = As + (w * 16 + l16) * 32 + quad * 8;

    float bia[4];
#pragma unroll
    for (int n = 0; n < 4; n++) bia[n] = bO[jb + n * 16 + l16];

    const int qr = q0 + w * 16 + quad * 4;

    floatx4 s1[4];
    // ---- Phases A & B: K=768 GEMM over Zb[2b+pp] ----
#pragma unroll 1
    for (int pp = 0; pp < 2; pp++) {
        const ushort* Zp = Zb + (size_t)(b_ * 2 + pp) * (NH * SS * DH);
        floatx4 acc[4];
#pragma unroll
        for (int n = 0; n < 4; n++) acc[n] = (floatx4){0.f, 0.f, 0.f, 0.f};
        for (int kt = 0; kt < 24; kt++) {
            const int k0 = kt * 32;
            __syncthreads();
            gld_lds16(Zp + (size_t)(k0 >> 6) * (SS * DH) + (size_t)arow * DH + (k0 & 63) + scol, lA);
            gld_lds16(gB + k0, lB);
            asm volatile("s_waitcnt vmcnt(0)" ::: "memory");
            __syncthreads();
            short8 a = *(const short8*)(Afrag);
#pragma unroll
            for (int n = 0; n < 4; n++) {
                short8 b = *(const short8*)(Bs + (n * 16 + l16) * 32 + quad * 8);
                acc[n] = __builtin_amdgcn_mfma_f32_16x16x32_bf16(a, b, acc[n], 0, 0, 0);
            }
        }
        float* obase = out + ((size_t)(b_ * 14 + pp) * SS) * DM;
#pragma unroll
        for (int n = 0; n < 4; n++) {
            const int d = jb + n * 16 + l16;
#pragma unroll
            for (int r = 0; r < 4; r++) {
                const float v = acc[n][r] + bia[n];
                obase[(size_t)(qr + r) * DM + d] = v;
                if (pp == 1) s1[n][r] = v;
            }
        }
    }

    // ---- Phase C: 12 per-head diff GEMMs, K=64 ----
    const ushort* Zdb = Zd + (size_t)b_ * (NH * SS * DH);
#pragma unroll 1
    for (int k = 0; k < NH; k++) {
        const ushort* Zdk = Zdb + (size_t)k * (SS * DH);
        floatx4 acc[4];
#pragma unroll
        for (int n = 0; n < 4; n++) acc[n] = (floatx4){0.f, 0.f, 0.f, 0.f};
#pragma unroll
        for (int kt = 0; kt < 2; kt++) {
            const int k0 = kt * 32;
            __syncthreads();
            gld_lds16(Zdk + (size_t)arow * DH + k0 + scol, lA);
            gld_lds16(gB + k * DH + k0, lB);
            asm volatile("s_waitcnt vmcnt(0)" ::: "memory");
            __syncthreads();
            short8 a = *(const short8*)(Afrag);
#pragma unroll
            for (int n = 0; n < 4; n++) {
                short8 b = *(const short8*)(Bs + (n * 16 + l16) * 32 + quad * 8);
                acc[n] = __builtin_amdgcn_mfma_f32_16x16x32_bf16(a, b, acc[n], 0, 0, 0);
            }
        }
        float* obase = out + ((size_t)(b_ * 14 + 2 + k) * SS) * DM;
#pragma unroll
        for (int n = 0; n < 4; n++) {
            const int d = jb + n * 16 + l16;
#pragma unroll
            for (int r = 0; r < 4; r++)
                obase[(size_t)(qr + r) * DM + d] = acc[n][r] + s1[n][r];
        }
    }
}

extern "C" void kernel_launch(void* const* d_in, const int* in_sizes, int n_in,
                              void* d_out, int out_size, void* d_ws, size_t ws_size,
                              hipStream_t stream)
{
    const float* x0 = (const float*)d_in[0];
    const float* x1 = (const float*)d_in[1];
    const float* WQ = (const float*)d_in[2];
    const float* bQ = (const float*)d_in[3];
    const float* WK = (const float*)d_in[4];
    const float* bK = (const float*)d_in[5];
    const float* WV = (const float*)d_in[6];
    const float* bV = (const float*)d_in[7];
    const float* WO = (const float*)d_in[8];
    const float* bO = (const float*)d_in[9];
    float* out = (float*)d_out;

    ushort* ub   = (ushort*)d_ws;
    ushort* Qb   = ub;                        // 6291456
    ushort* Kb   = Qb + 6291456;
    ushort* Vtb  = Kb + 6291456;
    ushort* xb   = Vtb + 6291456;
    ushort* WbT  = xb + 6291456;              // 1769472
    ushort* Zb   = WbT + 1769472;             // 6291456
    ushort* WObT = Zb + 6291456;              // 589824
    ushort* Zd   = WObT + 589824;             // 3145728

    prep_k<<<dim3(3648), 256, 0, stream>>>(x0, x1, WQ, WK, WV, WO, xb, WbT, WObT);
    qkv_mfma_k<<<dim3(18, 64), 256, 0, stream>>>(xb, WbT, bQ, bK, bV, Qb, Kb, Vtb);
    attn_mfma_k<<<dim3(768), 256, 0, stream>>>(Qb, Kb, Vtb, Zb);
    zdiff_k<<<dim3(1536), 256, 0, stream>>>(Zb, Zd);
    outproj_k<<<dim3(12, 16, 4), 256, 0, stream>>>(Zb, Zd, WObT, bO, out);
}